// Round 6
// baseline (570.104 us; speedup 1.0000x reference)
//
#include <hip/hip_runtime.h>
#include <hip/hip_cooperative_groups.h>
#include <math.h>

namespace cg = cooperative_groups;

#define CTR_CNT2 0   // |A2|
#define CTR_CNT1 1   // |A1|
#define CTR_E2   2   // #edges into node 0
#define CTR_EB   3   // #edges into A2
#define CTR_EC   4   // #edges into A1

// ---------------- wave helpers (wave64) ----------------
__device__ inline float wave_sum(float v){
  #pragma unroll
  for (int off = 1; off < 64; off <<= 1) v += __shfl_xor(v, off, 64);
  return v;
}
__device__ inline float wave_max(float v){
  #pragma unroll
  for (int off = 1; off < 64; off <<= 1) v = fmaxf(v, __shfl_xor(v, off, 64));
  return v;
}

// prefetch helper: read every-64th 1KB tile (slice) of A, keep-alive
__device__ inline float pf_arr(const float* A, int nfloats, int slice, int tid){
  const float4* A4 = (const float4*)A;
  int n4 = nfloats >> 2;
  float a = 0.f;
  for (int t = slice; t * 256 < n4; t += 64){
    int j = t * 256 + tid;
    if (j < n4){ float4 v = A4[j]; a += v.x + v.y + v.z + v.w; }
  }
  return a;
}

struct MegaParams {
  const float* x; const int* ei;
  const float *Wl0,*bl0,*Wr0,*br0,*att0,*bias0;
  const float *Wl1,*bl1,*Wr1,*br1,*att1,*bias1;
  const float *Wl2,*bl2,*Wr2,*br2,*att2,*bias2;
  const float *g0,*be0,*g1,*be1,*g2,*be2;
  const float *rw1,*rb1,*rw2,*rb2;
  int N, E;
  int *ctr,*flag1,*flag2,*list1,*list2,*E2src,*EBsrc,*EBdst,*ECsrc,*ECdst;
  int *rowptr0,*rowptr1,*srcs0s,*srcs1s;
  float *xr2,*xl2,*xl1,*xr1buf;
  float* out;
};

__global__ __launch_bounds__(256, 2) void k_mega(MegaParams P){
  cg::grid_group grid = cg::this_grid();
  const int tid  = threadIdx.x;
  const int h    = tid >> 6;
  const int lane = tid & 63;
  const int gsz  = gridDim.x * 256;
  const int gid  = blockIdx.x * 256 + tid;

  __shared__ int   s_cnts[4096];
  __shared__ int   s_cur[4096];
  __shared__ int   s_scan[256];
  __shared__ int   s_carry;
  __shared__ float s_lg[512];   // 4 heads x 128
  __shared__ float s_p[512];
  __shared__ float s_xf[128];
  __shared__ int   s_xi[128];
  __shared__ float s_hs[256];
  __shared__ float s_red[4];
  __shared__ int   s_b0, s_b1, s_b2;

  // ---------- phase 0: init flags/ctr ----------
  for (int i = gid; i < P.N; i += gsz){
    P.flag1[i] = 0;
    P.flag2[i] = (i == 0) ? 1 : 0;   // node 0 = A2 index 0
  }
  if (gid < 8) P.ctr[gid] = (gid == CTR_CNT2) ? 1 : 0;
  if (gid == 0) P.list2[0] = 0;
  grid.sync();

  // ---------- phase A: edges into node 0; discover A2 ----------
  {
    int chunk = (P.E + gridDim.x - 1) / gridDim.x;
    int lo = blockIdx.x * chunk, hi = min(P.E, lo + chunk);
    if (tid == 0){ s_b0 = 0; s_b1 = 0; }
    __syncthreads();
    int cnt = 0;
    for (int e = lo + tid; e < hi; e += 256) if (P.ei[P.E + e] == 0) cnt++;
    if (cnt) atomicAdd(&s_b0, cnt);
    __syncthreads();
    if (tid == 0) s_b2 = s_b0 ? atomicAdd(&P.ctr[CTR_E2], s_b0) : 0;
    __syncthreads();
    for (int e = lo + tid; e < hi; e += 256){
      if (P.ei[P.E + e] != 0) continue;
      int s = P.ei[e];
      P.E2src[s_b2 + atomicAdd(&s_b1, 1)] = s;
      if (atomicCAS(&P.flag2[s], 0, -1) == 0){
        int idx = atomicAdd(&P.ctr[CTR_CNT2], 1);
        P.list2[idx] = s;
        P.flag2[s] = idx + 1;
      }
    }
  }
  grid.sync();

  // ---------- phase seed: A1 seeded with A2 (a1idx == a2idx) ----------
  if (blockIdx.x == 0){
    int cnt2 = P.ctr[CTR_CNT2];
    for (int i = tid; i < cnt2; i += 256){
      int v = P.list2[i];
      P.list1[i] = v;
      P.flag1[v] = i + 1;
    }
    __syncthreads();
    if (tid == 0) P.ctr[CTR_CNT1] = cnt2;
  }
  grid.sync();

  // ---------- phase B: compact edges into A2; discover A1 ----------
  {
    int chunk = (P.E + gridDim.x - 1) / gridDim.x;
    int lo = blockIdx.x * chunk, hi = min(P.E, lo + chunk);
    if (tid == 0){ s_b0 = 0; s_b1 = 0; }
    __syncthreads();
    int cnt = 0;
    for (int e = lo + tid; e < hi; e += 256) if (P.flag2[P.ei[P.E + e]] > 0) cnt++;
    if (cnt) atomicAdd(&s_b0, cnt);
    __syncthreads();
    if (tid == 0) s_b2 = s_b0 ? atomicAdd(&P.ctr[CTR_EB], s_b0) : 0;
    __syncthreads();
    for (int e = lo + tid; e < hi; e += 256){
      int f = P.flag2[P.ei[P.E + e]];
      if (f <= 0) continue;
      int s = P.ei[e];
      int p = s_b2 + atomicAdd(&s_b1, 1);
      P.EBsrc[p] = s; P.EBdst[p] = f - 1;
      if (atomicCAS(&P.flag1[s], 0, -1) == 0){
        int idx = atomicAdd(&P.ctr[CTR_CNT1], 1);
        P.list1[idx] = s;
        P.flag1[s] = idx + 1;
      }
    }
  }
  grid.sync();

  // ---------- phase C: block0 regroups B-edges; others compact C-edges ----------
  if (blockIdx.x == 0){
    int cnt2 = min(P.ctr[CTR_CNT2], 4096);
    int nB = P.ctr[CTR_EB];
    for (int i = tid; i < cnt2; i += 256) s_cnts[i] = 0;
    __syncthreads();
    for (int j = tid; j < nB; j += 256){
      int d = P.EBdst[j];
      if (d < 4096) atomicAdd(&s_cnts[d], 1);
    }
    __syncthreads();
    if (tid == 0) s_carry = 0;
    __syncthreads();
    for (int c0 = 0; c0 < cnt2; c0 += 256){
      int i = c0 + tid;
      int v = (i < cnt2) ? s_cnts[i] : 0;
      s_scan[tid] = v;
      __syncthreads();
      for (int off = 1; off < 256; off <<= 1){
        int t = (tid >= off) ? s_scan[tid - off] : 0;
        __syncthreads();
        s_scan[tid] += t;
        __syncthreads();
      }
      int excl = s_scan[tid] - v + s_carry;
      if (i < cnt2){ P.rowptr1[i] = excl; s_cur[i] = excl; }
      int tot = s_scan[255];
      __syncthreads();
      if (tid == 0) s_carry += tot;
      __syncthreads();
    }
    if (tid == 0) P.rowptr1[cnt2] = s_carry;
    __syncthreads();
    for (int j = tid; j < nB; j += 256){
      int d = P.EBdst[j];
      if (d < 4096){
        int pos = atomicAdd(&s_cur[d], 1);
        P.srcs1s[pos] = P.flag1[P.EBsrc[j]] - 1;  // a1 index
      }
    }
  } else {
    int nblk = gridDim.x - 1;
    int chunk = (P.E + nblk - 1) / nblk;
    int lo = (blockIdx.x - 1) * chunk, hi = min(P.E, lo + chunk);
    if (tid == 0){ s_b0 = 0; s_b1 = 0; }
    __syncthreads();
    int cnt = 0;
    for (int e = lo + tid; e < hi; e += 256) if (P.flag1[P.ei[P.E + e]] > 0) cnt++;
    if (cnt) atomicAdd(&s_b0, cnt);
    __syncthreads();
    if (tid == 0) s_b2 = s_b0 ? atomicAdd(&P.ctr[CTR_EC], s_b0) : 0;
    __syncthreads();
    for (int e = lo + tid; e < hi; e += 256){
      int f = P.flag1[P.ei[P.E + e]];
      if (f <= 0) continue;
      int p = s_b2 + atomicAdd(&s_b1, 1);
      P.ECsrc[p] = P.ei[e]; P.ECdst[p] = f - 1;
    }
  }
  grid.sync();

  // ---------- phase regC (block0) + L2 weight prefetch (others) ----------
  if (blockIdx.x == 0){
    int cnt1 = min(P.ctr[CTR_CNT1], 4096);
    int nC = P.ctr[CTR_EC];
    for (int i = tid; i < cnt1; i += 256) s_cnts[i] = 0;
    __syncthreads();
    for (int j = tid; j < nC; j += 256){
      int d = P.ECdst[j];
      if (d < 4096) atomicAdd(&s_cnts[d], 1);
    }
    __syncthreads();
    if (tid == 0) s_carry = 0;
    __syncthreads();
    for (int c0 = 0; c0 < cnt1; c0 += 256){
      int i = c0 + tid;
      int v = (i < cnt1) ? s_cnts[i] : 0;
      s_scan[tid] = v;
      __syncthreads();
      for (int off = 1; off < 256; off <<= 1){
        int t = (tid >= off) ? s_scan[tid - off] : 0;
        __syncthreads();
        s_scan[tid] += t;
        __syncthreads();
      }
      int excl = s_scan[tid] - v + s_carry;
      if (i < cnt1){ P.rowptr0[i] = excl; s_cur[i] = excl; }
      int tot = s_scan[255];
      __syncthreads();
      if (tid == 0) s_carry += tot;
      __syncthreads();
    }
    if (tid == 0) P.rowptr0[cnt1] = s_carry;
    __syncthreads();
    for (int j = tid; j < nC; j += 256){
      int d = P.ECdst[j];
      if (d < 4096){
        int pos = atomicAdd(&s_cur[d], 1);
        P.srcs0s[pos] = P.ECsrc[j];   // node id
      }
    }
  } else {
    // warm this XCD's L2 with the weights L0/L1 are about to stream
    int slice = (blockIdx.x - 1) & 63;
    float a = 0.f;
    a += pf_arr(P.Wl1, 256 * 256, slice, tid);
    a += pf_arr(P.Wr1, 256 * 256, slice, tid);
    a += pf_arr(P.Wl2, 256 * 64,  slice, tid);
    a += pf_arr(P.Wr2, 256 * 64,  slice, tid);
    a += pf_arr(P.x,   P.N,       slice, tid);
    asm volatile("" :: "v"(a));
  }
  grid.sync();

  // ---------- phase L0: two-phase softmax agg + LN + ELU + fused L1 GEMVs ----------
  {
    int cnt1 = min(P.ctr[CTR_CNT1], 4096);
    float wl = P.Wl0[tid], blv = P.bl0[tid], wr = P.Wr0[tid], brv = P.br0[tid];
    float at = P.att0[tid], bs = P.bias0[tid], gv = P.g0[tid], bev = P.be0[tid];
    float bl1v = P.bl1[tid], br1v = P.br1[tid];
    for (int i = blockIdx.x; i < cnt1; i += gridDim.x){
      int v = P.list1[i];
      float xrc = fmaf(P.x[v], wr, brv);
      int r0 = P.rowptr0[i], r1 = P.rowptr0[i + 1];
      float m = -INFINITY, S = 0.f, acc = 0.f;
      for (int e0 = r0; e0 <= r1; e0 += 128){   // slot r1 = synthetic self-loop
        int n = min(128, r1 + 1 - e0);
        for (int j = 0; j < n; ++j){
          int e = e0 + j;
          int s = (e < r1) ? P.srcs0s[e] : v;
          float xv = P.x[s];
          float aa = fmaf(xv, wl, blv) + xrc;
          aa = (aa > 0.f) ? aa : 0.2f * aa;
          float lg = wave_sum(at * aa);
          if (lane == 0) s_lg[h * 128 + j] = lg;
          if (tid == 0)  s_xf[j] = xv;
        }
        __syncthreads();
        float mc = -INFINITY;
        for (int j = lane; j < n; j += 64) mc = fmaxf(mc, s_lg[h * 128 + j]);
        mc = wave_max(mc);
        float mn = fmaxf(m, mc);
        float sc = expf(m - mn);
        float Sc = 0.f;
        for (int j = lane; j < n; j += 64){
          float p = expf(s_lg[h * 128 + j] - mn);
          s_p[h * 128 + j] = p;
          Sc += p;
        }
        Sc = wave_sum(Sc);
        S = fmaf(S, sc, Sc);
        float an = acc * sc;
        for (int j = 0; j < n; ++j)
          an = fmaf(s_p[h * 128 + j], fmaf(s_xf[j], wl, blv), an);
        acc = an;
        m = mn;
        __syncthreads();
      }
      float o = acc / (S + 1e-16f) + bs;
      float s1 = wave_sum(o);
      if (lane == 0) s_red[h] = s1;
      __syncthreads();
      float mu = (s_red[0] + s_red[1] + s_red[2] + s_red[3]) * (1.f / 256.f);
      float dv = o - mu;
      __syncthreads();
      float s2 = wave_sum(dv * dv);
      if (lane == 0) s_red[h] = s2;
      __syncthreads();
      float var = (s_red[0] + s_red[1] + s_red[2] + s_red[3]) * (1.f / 256.f);
      float y = dv * rsqrtf(var + 1e-5f) * gv + bev;
      float h0v = (y > 0.f) ? y : expm1f(y);
      s_hs[tid] = h0v;
      __syncthreads();
      float p0 = 0.f, p1 = 0.f;
      #pragma unroll 8
      for (int k = 0; k < 256; k += 2){
        p0 = fmaf(s_hs[k],     P.Wl1[(size_t)k * 256 + tid],       p0);
        p1 = fmaf(s_hs[k + 1], P.Wl1[(size_t)(k + 1) * 256 + tid], p1);
      }
      P.xl1[(size_t)i * 256 + tid] = bl1v + p0 + p1;
      int f2 = P.flag2[v];
      if (f2 > 0){
        float q0 = 0.f, q1 = 0.f;
        #pragma unroll 8
        for (int k = 0; k < 256; k += 2){
          q0 = fmaf(s_hs[k],     P.Wr1[(size_t)k * 256 + tid],       q0);
          q1 = fmaf(s_hs[k + 1], P.Wr1[(size_t)(k + 1) * 256 + tid], q1);
        }
        P.xr1buf[(size_t)(f2 - 1) * 256 + tid] = br1v + q0 + q1;
      }
      __syncthreads();
    }
  }
  grid.sync();

  // ---------- phase L1: two-phase softmax agg + LN + ELU + fused L2 GEMVs ----------
  {
    int cnt2 = min(P.ctr[CTR_CNT2], 1024);
    float at = P.att1[tid], bs = P.bias1[tid], gv = P.g1[tid], bev = P.be1[tid];
    for (int i = blockIdx.x; i < cnt2; i += gridDim.x){
      float xrc = P.xr1buf[(size_t)i * 256 + tid];
      int r0 = P.rowptr1[i], r1 = P.rowptr1[i + 1];
      float m = -INFINITY, S = 0.f, acc = 0.f;
      for (int e0 = r0; e0 <= r1; e0 += 128){
        int n = min(128, r1 + 1 - e0);
        for (int j = 0; j < n; ++j){
          int e = e0 + j;
          int si = (e < r1) ? P.srcs1s[e] : i;   // self: a1idx == a2idx == i
          float xls = P.xl1[(size_t)si * 256 + tid];
          float aa = xls + xrc;
          aa = (aa > 0.f) ? aa : 0.2f * aa;
          float lg = wave_sum(at * aa);
          if (lane == 0) s_lg[h * 128 + j] = lg;
          if (tid == 0)  s_xi[j] = si;
        }
        __syncthreads();
        float mc = -INFINITY;
        for (int j = lane; j < n; j += 64) mc = fmaxf(mc, s_lg[h * 128 + j]);
        mc = wave_max(mc);
        float mn = fmaxf(m, mc);
        float sc = expf(m - mn);
        float Sc = 0.f;
        for (int j = lane; j < n; j += 64){
          float p = expf(s_lg[h * 128 + j] - mn);
          s_p[h * 128 + j] = p;
          Sc += p;
        }
        Sc = wave_sum(Sc);
        S = fmaf(S, sc, Sc);
        float an = acc * sc;
        for (int j = 0; j < n; ++j)
          an = fmaf(s_p[h * 128 + j], P.xl1[(size_t)s_xi[j] * 256 + tid], an);
        acc = an;
        m = mn;
        __syncthreads();
      }
      float o = acc / (S + 1e-16f) + bs;
      float s1 = wave_sum(o);
      if (lane == 0) s_red[h] = s1;
      __syncthreads();
      float mu = (s_red[0] + s_red[1] + s_red[2] + s_red[3]) * (1.f / 256.f);
      float dv = o - mu;
      __syncthreads();
      float s2 = wave_sum(dv * dv);
      if (lane == 0) s_red[h] = s2;
      __syncthreads();
      float var = (s_red[0] + s_red[1] + s_red[2] + s_red[3]) * (1.f / 256.f);
      float y = dv * rsqrtf(var + 1e-5f) * gv + bev;
      float h1v = (y > 0.f) ? y : expm1f(y);
      s_hs[tid] = h1v;
      __syncthreads();
      if (tid < 64){
        float a0 = 0.f, a1 = 0.f;
        #pragma unroll 8
        for (int k = 0; k < 256; k += 2){
          a0 = fmaf(s_hs[k],     P.Wl2[(size_t)k * 64 + tid],       a0);
          a1 = fmaf(s_hs[k + 1], P.Wl2[(size_t)(k + 1) * 64 + tid], a1);
        }
        P.xl2[(size_t)i * 64 + tid] = P.bl2[tid] + a0 + a1;
        if (i == 0){
          float b0 = 0.f, b1 = 0.f;
          #pragma unroll 8
          for (int k = 0; k < 256; k += 2){
            b0 = fmaf(s_hs[k],     P.Wr2[(size_t)k * 64 + tid],       b0);
            b1 = fmaf(s_hs[k + 1], P.Wr2[(size_t)(k + 1) * 64 + tid], b1);
          }
          P.xr2[tid] = P.br2[tid] + b0 + b1;
        }
      }
      __syncthreads();
    }
  }
  grid.sync();

  // ---------- phase final: node-0 layer-2 agg + LN + ELU + head MLP ----------
  // single wave, no __syncthreads (wave-coherent LDS)
  if (blockIdx.x == 0 && tid < 64){
    float xr = P.xr2[tid], at = P.att2[tid];
    int ne = P.ctr[CTR_E2];
    float m = -INFINITY, S = 0.f, acc = 0.f;
    for (int e0 = 0; e0 <= ne; e0 += 128){
      int n = min(128, ne + 1 - e0);
      for (int j = 0; j < n; ++j){
        int e = e0 + j;
        int idx = (e < ne) ? (P.flag2[P.E2src[e]] - 1) : 0;
        float xls = P.xl2[(size_t)idx * 64 + tid];
        float aa = xls + xr;
        aa = (aa > 0.f) ? aa : 0.2f * aa;
        float lg = wave_sum(at * aa);
        if (tid == 0){ s_lg[j] = lg; s_xi[j] = idx; }
      }
      float mc = -INFINITY;
      for (int j = tid; j < n; j += 64) mc = fmaxf(mc, s_lg[j]);
      mc = wave_max(mc);
      float mn = fmaxf(m, mc);
      float sc = expf(m - mn);
      float Sc = 0.f;
      for (int j = tid; j < n; j += 64){
        float p = expf(s_lg[j] - mn);
        s_p[j] = p;
        Sc += p;
      }
      Sc = wave_sum(Sc);
      S = fmaf(S, sc, Sc);
      float an = acc * sc;
      for (int j = 0; j < n; ++j)
        an = fmaf(s_p[j], P.xl2[(size_t)s_xi[j] * 64 + tid], an);
      acc = an;
      m = mn;
    }
    float o = acc / (S + 1e-16f) + P.bias2[tid];
    float mu = wave_sum(o) * (1.f / 64.f);
    float dv = o - mu;
    float var = wave_sum(dv * dv) * (1.f / 64.f);
    float y = dv * rsqrtf(var + 1e-5f) * P.g2[tid] + P.be2[tid];
    float hv = (y > 0.f) ? y : expm1f(y);
    s_hs[tid] = hv;
    float contrib = 0.f;
    if (tid < 32){
      float a = P.rb1[tid];
      #pragma unroll 8
      for (int c = 0; c < 64; ++c) a = fmaf(s_hs[c], P.rw1[c * 32 + tid], a);
      float z = 0.5f * a * (1.f + erff(a * 0.70710678118654752f));
      contrib = z * P.rw2[tid];
    }
    float sfin = wave_sum(contrib);
    if (tid == 0) P.out[0] = sfin + P.rb2[0];
  }
}

// ======================= fallback path (round-5 kernels) =======================
__global__ void k_init(int* __restrict__ flag1, int* __restrict__ flag2,
                       int* __restrict__ list2, int* __restrict__ ctr, int N){
  int i = blockIdx.x * 256 + threadIdx.x;
  if (i < N){
    flag1[i] = 0;
    flag2[i] = (i == 0) ? 1 : 0;
  }
  if (i < 8) ctr[i] = (i == CTR_CNT2) ? 1 : 0;
  if (i == 0) list2[0] = 0;
}

__global__ __launch_bounds__(256) void k_passA(const int* __restrict__ ei, int E,
                        int* __restrict__ flag2, int* __restrict__ list2,
                        int* __restrict__ E2src, int* __restrict__ ctr){
  __shared__ int bcnt, lcur, gbase;
  int tid = threadIdx.x;
  int chunk = (E + gridDim.x - 1) / gridDim.x;
  int lo = blockIdx.x * chunk;
  int hi = min(E, lo + chunk);
  if (tid == 0){ bcnt = 0; lcur = 0; }
  __syncthreads();
  int cnt = 0;
  for (int e = lo + tid; e < hi; e += 256) if (ei[E + e] == 0) cnt++;
  if (cnt) atomicAdd(&bcnt, cnt);
  __syncthreads();
  if (tid == 0) gbase = bcnt ? atomicAdd(&ctr[CTR_E2], bcnt) : 0;
  __syncthreads();
  for (int e = lo + tid; e < hi; e += 256){
    if (ei[E + e] != 0) continue;
    int s = ei[e];
    E2src[gbase + atomicAdd(&lcur, 1)] = s;
    if (atomicCAS(&flag2[s], 0, -1) == 0){
      int idx = atomicAdd(&ctr[CTR_CNT2], 1);
      list2[idx] = s;
      flag2[s] = idx + 1;
    }
  }
}

__global__ void k_seed(const int* __restrict__ list2, int* __restrict__ list1,
                       int* __restrict__ flag1, int* __restrict__ ctr){
  int cnt2 = ctr[CTR_CNT2];
  for (int i = threadIdx.x; i < cnt2; i += 256){
    int v = list2[i];
    list1[i] = v;
    flag1[v] = i + 1;
  }
  if (threadIdx.x == 0) ctr[CTR_CNT1] = cnt2;
}

__global__ __launch_bounds__(256) void k_passB(const int* __restrict__ ei, int E,
                        const int* __restrict__ flag2,
                        int* __restrict__ flag1, int* __restrict__ list1,
                        int* __restrict__ EBsrc, int* __restrict__ EBdst,
                        int* __restrict__ ctr){
  __shared__ int bcnt, lcur, gbase;
  int tid = threadIdx.x;
  int chunk = (E + gridDim.x - 1) / gridDim.x;
  int lo = blockIdx.x * chunk;
  int hi = min(E, lo + chunk);
  if (tid == 0){ bcnt = 0; lcur = 0; }
  __syncthreads();
  int cnt = 0;
  for (int e = lo + tid; e < hi; e += 256) if (flag2[ei[E + e]] > 0) cnt++;
  if (cnt) atomicAdd(&bcnt, cnt);
  __syncthreads();
  if (tid == 0) gbase = bcnt ? atomicAdd(&ctr[CTR_EB], bcnt) : 0;
  __syncthreads();
  for (int e = lo + tid; e < hi; e += 256){
    int f = flag2[ei[E + e]];
    if (f <= 0) continue;
    int s = ei[e];
    int p = gbase + atomicAdd(&lcur, 1);
    EBsrc[p] = s; EBdst[p] = f - 1;
    if (atomicCAS(&flag1[s], 0, -1) == 0){
      int idx = atomicAdd(&ctr[CTR_CNT1], 1);
      list1[idx] = s;
      flag1[s] = idx + 1;
    }
  }
}

__global__ __launch_bounds__(256) void k_passC_regB(const int* __restrict__ ei, int E,
    const int* __restrict__ flag1,
    int* __restrict__ ECsrc, int* __restrict__ ECdst, int* __restrict__ ctr,
    const int* __restrict__ EBsrc, const int* __restrict__ EBdst,
    int* __restrict__ rowptr1, int* __restrict__ srcs1s){
  int tid = threadIdx.x;
  if (blockIdx.x == 0){
    __shared__ int cnts[1024];
    __shared__ int cur[1024];
    int cnt2 = ctr[CTR_CNT2], nB = ctr[CTR_EB];
    for (int i = tid; i < cnt2; i += 256) cnts[i] = 0;
    __syncthreads();
    for (int j = tid; j < nB; j += 256) atomicAdd(&cnts[EBdst[j]], 1);
    __syncthreads();
    if (tid == 0){
      int run = 0;
      for (int k = 0; k < cnt2; ++k){ rowptr1[k] = run; cur[k] = run; run += cnts[k]; }
      rowptr1[cnt2] = run;
    }
    __syncthreads();
    for (int j = tid; j < nB; j += 256){
      int pos = atomicAdd(&cur[EBdst[j]], 1);
      srcs1s[pos] = flag1[EBsrc[j]] - 1;
    }
  } else {
    __shared__ int bcnt, lcur, gbase;
    int nblk = gridDim.x - 1;
    int chunk = (E + nblk - 1) / nblk;
    int lo = (blockIdx.x - 1) * chunk;
    int hi = min(E, lo + chunk);
    if (tid == 0){ bcnt = 0; lcur = 0; }
    __syncthreads();
    int cnt = 0;
    for (int e = lo + tid; e < hi; e += 256) if (flag1[ei[E + e]] > 0) cnt++;
    if (cnt) atomicAdd(&bcnt, cnt);
    __syncthreads();
    if (tid == 0) gbase = bcnt ? atomicAdd(&ctr[CTR_EC], bcnt) : 0;
    __syncthreads();
    for (int e = lo + tid; e < hi; e += 256){
      int f = flag1[ei[E + e]];
      if (f <= 0) continue;
      int p = gbase + atomicAdd(&lcur, 1);
      ECsrc[p] = ei[e]; ECdst[p] = f - 1;
    }
  }
}

__global__ __launch_bounds__(256) void k_regC(const int* __restrict__ ECsrc,
    const int* __restrict__ ECdst,
    int* __restrict__ rowptr0, int* __restrict__ srcs0s,
    const int* __restrict__ ctr){
  __shared__ int cnts[8192];
  __shared__ int cur[8192];
  int tid = threadIdx.x;
  int cnt1 = ctr[CTR_CNT1], nC = ctr[CTR_EC];
  if (cnt1 > 8192) cnt1 = 8192;
  for (int i = tid; i < cnt1; i += 256) cnts[i] = 0;
  __syncthreads();
  for (int j = tid; j < nC; j += 256){
    int d = ECdst[j];
    if (d < 8192) atomicAdd(&cnts[d], 1);
  }
  __syncthreads();
  if (tid == 0){
    int run = 0;
    for (int k = 0; k < cnt1; ++k){ rowptr0[k] = run; cur[k] = run; run += cnts[k]; }
    rowptr0[cnt1] = run;
  }
  __syncthreads();
  for (int j = tid; j < nC; j += 256){
    int d = ECdst[j];
    if (d < 8192){
      int pos = atomicAdd(&cur[d], 1);
      srcs0s[pos] = ECsrc[j];
    }
  }
}

__global__ __launch_bounds__(256) void k_L0(const float* __restrict__ x,
    const float* __restrict__ Wl0, const float* __restrict__ bl0,
    const float* __restrict__ Wr0, const float* __restrict__ br0,
    const float* __restrict__ att0, const float* __restrict__ bias0,
    const float* __restrict__ g0, const float* __restrict__ be0,
    const float* __restrict__ Wl1, const float* __restrict__ bl1,
    const float* __restrict__ Wr1, const float* __restrict__ br1,
    const int* __restrict__ list1, const int* __restrict__ rowptr0,
    const int* __restrict__ srcs0s, const int* __restrict__ flag2,
    const int* __restrict__ ctr,
    float* __restrict__ xl1, float* __restrict__ xr1buf){
  int tid = threadIdx.x, h = tid >> 6, lane = tid & 63;
  float wl = Wl0[tid], blv = bl0[tid], wr = Wr0[tid], brv = br0[tid];
  float at = att0[tid], bs = bias0[tid], gv = g0[tid], bev = be0[tid];
  float bl1v = bl1[tid], br1v = br1[tid];
  __shared__ float red[4];
  __shared__ float hs[256];
  int cnt1 = ctr[CTR_CNT1];
  for (int i = blockIdx.x; i < cnt1; i += gridDim.x){
    int v = list1[i];
    float xr = fmaf(x[v], wr, brv);
    int r0 = rowptr0[i], r1 = rowptr0[i + 1];
    float m = -INFINITY, ssum = 0.f, acc = 0.f;
    for (int e = r0; e <= r1; ++e){
      int s = (e < r1) ? srcs0s[e] : v;
      float xls = fmaf(x[s], wl, blv);
      float a = xls + xr;
      a = (a > 0.f) ? a : 0.2f * a;
      float lg = wave_sum(at * a);
      float mn = fmaxf(m, lg);
      float sc = expf(m - mn), p = expf(lg - mn);
      ssum = fmaf(ssum, sc, p);
      acc  = fmaf(acc,  sc, p * xls);
      m = mn;
    }
    float o = acc / (ssum + 1e-16f) + bs;
    float s1 = wave_sum(o);
    if (lane == 0) red[h] = s1;
    __syncthreads();
    float mu = (red[0] + red[1] + red[2] + red[3]) * (1.f / 256.f);
    float dv = o - mu;
    __syncthreads();
    float s2 = wave_sum(dv * dv);
    if (lane == 0) red[h] = s2;
    __syncthreads();
    float var = (red[0] + red[1] + red[2] + red[3]) * (1.f / 256.f);
    float y = dv * rsqrtf(var + 1e-5f) * gv + bev;
    float h0v = (y > 0.f) ? y : expm1f(y);
    hs[tid] = h0v;
    __syncthreads();
    float xlv = bl1v;
    #pragma unroll 8
    for (int k = 0; k < 256; ++k) xlv = fmaf(hs[k], Wl1[(size_t)k * 256 + tid], xlv);
    xl1[(size_t)i * 256 + tid] = xlv;
    int f2 = flag2[v];
    if (f2 > 0){
      float xrv = br1v;
      #pragma unroll 8
      for (int k = 0; k < 256; ++k) xrv = fmaf(hs[k], Wr1[(size_t)k * 256 + tid], xrv);
      xr1buf[(size_t)(f2 - 1) * 256 + tid] = xrv;
    }
    __syncthreads();
  }
}

__global__ __launch_bounds__(256) void k_L1(const float* __restrict__ xl1,
    const float* __restrict__ xr1buf,
    const float* __restrict__ att1, const float* __restrict__ bias1,
    const float* __restrict__ g1, const float* __restrict__ be1,
    const float* __restrict__ Wl2, const float* __restrict__ bl2,
    const float* __restrict__ Wr2, const float* __restrict__ br2,
    const int* __restrict__ rowptr1, const int* __restrict__ srcs1s,
    const int* __restrict__ ctr,
    float* __restrict__ xl2, float* __restrict__ xr2){
  int tid = threadIdx.x, h = tid >> 6, lane = tid & 63;
  float at = att1[tid];
  __shared__ float red[4];
  __shared__ float hs[256];
  int cnt2 = ctr[CTR_CNT2];
  for (int i = blockIdx.x; i < cnt2; i += gridDim.x){
    float xr = xr1buf[(size_t)i * 256 + tid];
    int r0 = rowptr1[i], r1 = rowptr1[i + 1];
    float m = -INFINITY, ssum = 0.f, acc = 0.f;
    for (int e = r0; e <= r1; ++e){
      int si = (e < r1) ? srcs1s[e] : i;
      float xls = xl1[(size_t)si * 256 + tid];
      float a = xls + xr;
      a = (a > 0.f) ? a : 0.2f * a;
      float lg = wave_sum(at * a);
      float mn = fmaxf(m, lg);
      float sc = expf(m - mn), p = expf(lg - mn);
      ssum = fmaf(ssum, sc, p);
      acc  = fmaf(acc,  sc, p * xls);
      m = mn;
    }
    float o = acc / (ssum + 1e-16f) + bias1[tid];
    float s1 = wave_sum(o);
    if (lane == 0) red[h] = s1;
    __syncthreads();
    float mu = (red[0] + red[1] + red[2] + red[3]) * (1.f / 256.f);
    float dv = o - mu;
    __syncthreads();
    float s2 = wave_sum(dv * dv);
    if (lane == 0) red[h] = s2;
    __syncthreads();
    float var = (red[0] + red[1] + red[2] + red[3]) * (1.f / 256.f);
    float y = dv * rsqrtf(var + 1e-5f) * g1[tid] + be1[tid];
    float h1v = (y > 0.f) ? y : expm1f(y);
    hs[tid] = h1v;
    __syncthreads();
    if (tid < 64){
      float a2 = bl2[tid];
      #pragma unroll 8
      for (int k = 0; k < 256; ++k) a2 = fmaf(hs[k], Wl2[(size_t)k * 64 + tid], a2);
      xl2[(size_t)i * 64 + tid] = a2;
      if (i == 0){
        float b2 = br2[tid];
        #pragma unroll 8
        for (int k = 0; k < 256; ++k) b2 = fmaf(hs[k], Wr2[(size_t)k * 64 + tid], b2);
        xr2[tid] = b2;
      }
    }
    __syncthreads();
  }
}

__global__ __launch_bounds__(64) void k_final(const float* __restrict__ xl2,
    const float* __restrict__ xr2,
    const float* __restrict__ att2, const float* __restrict__ bias2,
    const float* __restrict__ g2, const float* __restrict__ be2,
    const float* __restrict__ rw1, const float* __restrict__ rb1,
    const float* __restrict__ rw2, const float* __restrict__ rb2,
    const int* __restrict__ E2src, const int* __restrict__ flag2,
    const int* __restrict__ ctr, float* __restrict__ out){
  int lane = threadIdx.x;
  float xr = xr2[lane], at = att2[lane];
  int ne = ctr[CTR_E2];
  float m = -INFINITY, ssum = 0.f, acc = 0.f;
  for (int e = 0; e <= ne; ++e){
    int idx = (e < ne) ? (flag2[E2src[e]] - 1) : 0;
    float xls = xl2[(size_t)idx * 64 + lane];
    float a = xls + xr;
    a = (a > 0.f) ? a : 0.2f * a;
    float lg = wave_sum(at * a);
    float mn = fmaxf(m, lg);
    float sc = expf(m - mn), p = expf(lg - mn);
    ssum = fmaf(ssum, sc, p);
    acc  = fmaf(acc,  sc, p * xls);
    m = mn;
  }
  float o = acc / (ssum + 1e-16f) + bias2[lane];
  float mu = wave_sum(o) * (1.f / 64.f);
  float dv = o - mu;
  float var = wave_sum(dv * dv) * (1.f / 64.f);
  float y = dv * rsqrtf(var + 1e-5f) * g2[lane] + be2[lane];
  float hv_v = (y > 0.f) ? y : expm1f(y);
  __shared__ float hv[64];
  hv[lane] = hv_v;
  __syncthreads();
  float contrib = 0.f;
  if (lane < 32){
    float a = rb1[lane];
    #pragma unroll 8
    for (int c = 0; c < 64; ++c) a = fmaf(hv[c], rw1[c * 32 + lane], a);
    float z = 0.5f * a * (1.f + erff(a * 0.70710678118654752f));
    contrib = z * rw2[lane];
  }
  float sfin = wave_sum(contrib);
  if (lane == 0) out[0] = sfin + rb2[0];
}

// ---------------- launch ----------------
extern "C" void kernel_launch(void* const* d_in, const int* in_sizes, int n_in,
                              void* d_out, int out_size, void* d_ws, size_t ws_size,
                              hipStream_t stream){
  const float* x    = (const float*)d_in[0];
  const int*   ei   = (const int*)  d_in[1];
  const float* Wl0  = (const float*)d_in[2];
  const float* bl0  = (const float*)d_in[3];
  const float* Wr0  = (const float*)d_in[4];
  const float* br0  = (const float*)d_in[5];
  const float* att0 = (const float*)d_in[6];
  const float* bias0= (const float*)d_in[7];
  const float* Wl1  = (const float*)d_in[8];
  const float* bl1  = (const float*)d_in[9];
  const float* Wr1  = (const float*)d_in[10];
  const float* br1  = (const float*)d_in[11];
  const float* att1 = (const float*)d_in[12];
  const float* bias1= (const float*)d_in[13];
  const float* Wl2  = (const float*)d_in[14];
  const float* bl2  = (const float*)d_in[15];
  const float* Wr2  = (const float*)d_in[16];
  const float* br2  = (const float*)d_in[17];
  const float* att2 = (const float*)d_in[18];
  const float* bias2= (const float*)d_in[19];
  const float* g0   = (const float*)d_in[20];
  const float* be0  = (const float*)d_in[21];
  const float* g1   = (const float*)d_in[22];
  const float* be1  = (const float*)d_in[23];
  const float* g2   = (const float*)d_in[24];
  const float* be2  = (const float*)d_in[25];
  const float* rw1  = (const float*)d_in[26];
  const float* rb1  = (const float*)d_in[27];
  const float* rw2  = (const float*)d_in[28];
  const float* rb2  = (const float*)d_in[29];

  const int N = in_sizes[0];        // 50000
  const int E = in_sizes[1] / 2;    // 800000

  char* ws = (char*)d_ws;
  size_t off = 0;
  auto alloc = [&](size_t bytes) -> char* {
    char* p = ws + off;
    off += (bytes + 255) & ~(size_t)255;
    return p;
  };
  int*   ctr     = (int*)  alloc(64);
  int*   flag1   = (int*)  alloc((size_t)N * 4);
  int*   flag2   = (int*)  alloc((size_t)N * 4);
  int*   list1   = (int*)  alloc((size_t)N * 4);
  int*   list2   = (int*)  alloc((size_t)N * 4);
  int*   E2src   = (int*)  alloc((size_t)E * 4);
  int*   EBsrc   = (int*)  alloc((size_t)E * 4);
  int*   EBdst   = (int*)  alloc((size_t)E * 4);
  int*   ECsrc   = (int*)  alloc((size_t)E * 4);
  int*   ECdst   = (int*)  alloc((size_t)E * 4);
  int*   rowptr0 = (int*)  alloc((size_t)(N + 1) * 4);
  int*   rowptr1 = (int*)  alloc((size_t)(N + 1) * 4);
  int*   srcs0s  = (int*)  alloc((size_t)E * 4);
  int*   srcs1s  = (int*)  alloc((size_t)E * 4);
  float* xr2     = (float*)alloc(64 * 4);
  float* xl2     = (float*)alloc((size_t)N * 64 * 4);
  float* xl1     = (float*)alloc((size_t)N * 256 * 4);
  float* xr1buf  = (float*)alloc((size_t)N * 256 * 4);
  (void)ws_size; (void)n_in; (void)out_size;

  MegaParams P;
  P.x = x; P.ei = ei;
  P.Wl0 = Wl0; P.bl0 = bl0; P.Wr0 = Wr0; P.br0 = br0; P.att0 = att0; P.bias0 = bias0;
  P.Wl1 = Wl1; P.bl1 = bl1; P.Wr1 = Wr1; P.br1 = br1; P.att1 = att1; P.bias1 = bias1;
  P.Wl2 = Wl2; P.bl2 = bl2; P.Wr2 = Wr2; P.br2 = br2; P.att2 = att2; P.bias2 = bias2;
  P.g0 = g0; P.be0 = be0; P.g1 = g1; P.be1 = be1; P.g2 = g2; P.be2 = be2;
  P.rw1 = rw1; P.rb1 = rb1; P.rw2 = rw2; P.rb2 = rb2;
  P.N = N; P.E = E;
  P.ctr = ctr; P.flag1 = flag1; P.flag2 = flag2; P.list1 = list1; P.list2 = list2;
  P.E2src = E2src; P.EBsrc = EBsrc; P.EBdst = EBdst; P.ECsrc = ECsrc; P.ECdst = ECdst;
  P.rowptr0 = rowptr0; P.rowptr1 = rowptr1; P.srcs0s = srcs0s; P.srcs1s = srcs1s;
  P.xr2 = xr2; P.xl2 = xl2; P.xl1 = xl1; P.xr1buf = xr1buf;
  P.out = (float*)d_out;

  void* args[] = { (void*)&P };
  hipError_t err = hipLaunchCooperativeKernel((void*)k_mega, dim3(512), dim3(256),
                                              args, 0, stream);
  if (err != hipSuccess){
    // deterministic fallback: round-5 multi-kernel path
    int nb = (N + 255) / 256;
    k_init      <<<nb, 256, 0, stream>>>(flag1, flag2, list2, ctr, N);
    k_passA     <<<256, 256, 0, stream>>>(ei, E, flag2, list2, E2src, ctr);
    k_seed      <<<1, 256, 0, stream>>>(list2, list1, flag1, ctr);
    k_passB     <<<256, 256, 0, stream>>>(ei, E, flag2, flag1, list1, EBsrc, EBdst, ctr);
    k_passC_regB<<<257, 256, 0, stream>>>(ei, E, flag1, ECsrc, ECdst, ctr,
                                          EBsrc, EBdst, rowptr1, srcs1s);
    k_regC      <<<1, 256, 0, stream>>>(ECsrc, ECdst, rowptr0, srcs0s, ctr);
    k_L0        <<<512, 256, 0, stream>>>(x, Wl0, bl0, Wr0, br0, att0, bias0, g0, be0,
                                          Wl1, bl1, Wr1, br1,
                                          list1, rowptr0, srcs0s, flag2, ctr, xl1, xr1buf);
    k_L1        <<<64, 256, 0, stream>>>(xl1, xr1buf, att1, bias1, g1, be1,
                                         Wl2, bl2, Wr2, br2,
                                         rowptr1, srcs1s, ctr, xl2, xr2);
    k_final     <<<1, 64, 0, stream>>>(xl2, xr2, att2, bias2, g2, be2,
                                       rw1, rb1, rw2, rb2, E2src, flag2, ctr, (float*)d_out);
  }
}

// Round 7
// 101.808 us; speedup vs baseline: 5.5998x; 5.5998x over previous
//
#include <hip/hip_runtime.h>
#include <math.h>

#define CTR_CNT2 0   // |A2|
#define CTR_CNT1 1   // |A1|
#define CTR_E2   2   // #edges into node 0
#define CTR_EB   3   // #edges into A2
#define CTR_EC   4   // #edges into A1

// ---------------- wave helpers (wave64) ----------------
__device__ inline float wave_sum(float v){
  #pragma unroll
  for (int off = 1; off < 64; off <<= 1) v += __shfl_xor(v, off, 64);
  return v;
}
__device__ inline float wave_max(float v){
  #pragma unroll
  for (int off = 1; off < 64; off <<= 1) v = fmaxf(v, __shfl_xor(v, off, 64));
  return v;
}

// ---------------- init ----------------
__global__ void k_init(int* __restrict__ flag1, int* __restrict__ flag2,
                       int* __restrict__ list2, int* __restrict__ ctr, int N){
  int i = blockIdx.x * 256 + threadIdx.x;
  if (i < N){
    flag1[i] = 0;
    flag2[i] = (i == 0) ? 1 : 0;   // node 0 = A2 index 0
  }
  if (i < 8) ctr[i] = (i == CTR_CNT2) ? 1 : 0;
  if (i == 0) list2[0] = 0;
}

// ---------------- pass A: edges into node 0; discover A2 ----------------
__global__ __launch_bounds__(256) void k_passA(const int* __restrict__ ei, int E,
                        int* __restrict__ flag2, int* __restrict__ list2,
                        int* __restrict__ E2src, int* __restrict__ ctr){
  __shared__ int bcnt, lcur, gbase;
  int tid = threadIdx.x;
  int chunk = (E + gridDim.x - 1) / gridDim.x;
  int lo = blockIdx.x * chunk;
  int hi = min(E, lo + chunk);
  if (tid == 0){ bcnt = 0; lcur = 0; }
  __syncthreads();
  int cnt = 0;
  for (int e = lo + tid; e < hi; e += 256) if (ei[E + e] == 0) cnt++;
  if (cnt) atomicAdd(&bcnt, cnt);
  __syncthreads();
  if (tid == 0) gbase = bcnt ? atomicAdd(&ctr[CTR_E2], bcnt) : 0;
  __syncthreads();
  for (int e = lo + tid; e < hi; e += 256){
    if (ei[E + e] != 0) continue;
    int s = ei[e];
    E2src[gbase + atomicAdd(&lcur, 1)] = s;
    if (atomicCAS(&flag2[s], 0, -1) == 0){
      int idx = atomicAdd(&ctr[CTR_CNT2], 1);
      list2[idx] = s;
      flag2[s] = idx + 1;
    }
  }
}

// ---------------- seed A1 with A2 (a1idx of an A2 node == its a2idx) ----------------
__global__ void k_seed(const int* __restrict__ list2, int* __restrict__ list1,
                       int* __restrict__ flag1, int* __restrict__ ctr){
  int cnt2 = ctr[CTR_CNT2];
  for (int i = threadIdx.x; i < cnt2; i += 256){
    int v = list2[i];
    list1[i] = v;
    flag1[v] = i + 1;
  }
  if (threadIdx.x == 0) ctr[CTR_CNT1] = cnt2;
}

// ---------------- pass B: compact edges into A2; discover A1 ----------------
__global__ __launch_bounds__(256) void k_passB(const int* __restrict__ ei, int E,
                        const int* __restrict__ flag2,
                        int* __restrict__ flag1, int* __restrict__ list1,
                        int* __restrict__ EBsrc, int* __restrict__ EBdst,
                        int* __restrict__ ctr){
  __shared__ int bcnt, lcur, gbase;
  int tid = threadIdx.x;
  int chunk = (E + gridDim.x - 1) / gridDim.x;
  int lo = blockIdx.x * chunk;
  int hi = min(E, lo + chunk);
  if (tid == 0){ bcnt = 0; lcur = 0; }
  __syncthreads();
  int cnt = 0;
  for (int e = lo + tid; e < hi; e += 256) if (flag2[ei[E + e]] > 0) cnt++;
  if (cnt) atomicAdd(&bcnt, cnt);
  __syncthreads();
  if (tid == 0) gbase = bcnt ? atomicAdd(&ctr[CTR_EB], bcnt) : 0;
  __syncthreads();
  for (int e = lo + tid; e < hi; e += 256){
    int f = flag2[ei[E + e]];
    if (f <= 0) continue;
    int s = ei[e];
    int p = gbase + atomicAdd(&lcur, 1);
    EBsrc[p] = s; EBdst[p] = f - 1;
    if (atomicCAS(&flag1[s], 0, -1) == 0){
      int idx = atomicAdd(&ctr[CTR_CNT1], 1);
      list1[idx] = s;
      flag1[s] = idx + 1;
    }
  }
}

// ---------------- pass C (blocks>=1, chunked) + regroup B-edges (block 0) ----------------
__global__ __launch_bounds__(256) void k_passC_regB(const int* __restrict__ ei, int E,
    const int* __restrict__ flag1,
    int* __restrict__ ECsrc, int* __restrict__ ECdst, int* __restrict__ ctr,
    const int* __restrict__ EBsrc, const int* __restrict__ EBdst,
    int* __restrict__ rowptr1, int* __restrict__ srcs1s){
  int tid = threadIdx.x;
  if (blockIdx.x == 0){
    __shared__ int cnts[1024];
    __shared__ int cur[1024];
    int cnt2 = ctr[CTR_CNT2], nB = ctr[CTR_EB];
    for (int i = tid; i < cnt2; i += 256) cnts[i] = 0;
    __syncthreads();
    for (int j = tid; j < nB; j += 256) atomicAdd(&cnts[EBdst[j]], 1);
    __syncthreads();
    if (tid == 0){
      int run = 0;
      for (int k = 0; k < cnt2; ++k){ rowptr1[k] = run; cur[k] = run; run += cnts[k]; }
      rowptr1[cnt2] = run;
    }
    __syncthreads();
    for (int j = tid; j < nB; j += 256){
      int pos = atomicAdd(&cur[EBdst[j]], 1);
      srcs1s[pos] = flag1[EBsrc[j]] - 1;   // a1 index
    }
  } else {
    __shared__ int bcnt, lcur, gbase;
    int nblk = gridDim.x - 1;
    int chunk = (E + nblk - 1) / nblk;
    int lo = (blockIdx.x - 1) * chunk;
    int hi = min(E, lo + chunk);
    if (tid == 0){ bcnt = 0; lcur = 0; }
    __syncthreads();
    int cnt = 0;
    for (int e = lo + tid; e < hi; e += 256) if (flag1[ei[E + e]] > 0) cnt++;
    if (cnt) atomicAdd(&bcnt, cnt);
    __syncthreads();
    if (tid == 0) gbase = bcnt ? atomicAdd(&ctr[CTR_EC], bcnt) : 0;
    __syncthreads();
    for (int e = lo + tid; e < hi; e += 256){
      int f = flag1[ei[E + e]];
      if (f <= 0) continue;
      int p = gbase + atomicAdd(&lcur, 1);
      ECsrc[p] = ei[e]; ECdst[p] = f - 1;
    }
  }
}

// ---------------- regroup C-edges into mini-CSR by a1 idx ----------------
__global__ __launch_bounds__(256) void k_regC(const int* __restrict__ ECsrc,
    const int* __restrict__ ECdst,
    int* __restrict__ rowptr0, int* __restrict__ srcs0s,
    const int* __restrict__ ctr){
  __shared__ int cnts[8192];
  __shared__ int cur[8192];
  int tid = threadIdx.x;
  int cnt1 = ctr[CTR_CNT1], nC = ctr[CTR_EC];
  if (cnt1 > 8192) cnt1 = 8192;
  for (int i = tid; i < cnt1; i += 256) cnts[i] = 0;
  __syncthreads();
  for (int j = tid; j < nC; j += 256){
    int d = ECdst[j];
    if (d < 8192) atomicAdd(&cnts[d], 1);
  }
  __syncthreads();
  if (tid == 0){
    int run = 0;
    for (int k = 0; k < cnt1; ++k){ rowptr0[k] = run; cur[k] = run; run += cnts[k]; }
    rowptr0[cnt1] = run;
  }
  __syncthreads();
  for (int j = tid; j < nC; j += 256){
    int d = ECdst[j];
    if (d < 8192){
      int pos = atomicAdd(&cur[d], 1);
      srcs0s[pos] = ECsrc[j];   // node id (layer 0 reads x[s] directly)
    }
  }
}

// ---------------- L0: rank-1 closed-form agg + LN + ELU + k-split float4 GEMVs ----------------
// out_agg[c] = Wl0[c] * (sum_e alpha_e x[s_e]) + bl0[c]   (xl0 is rank-1 in x)
__global__ __launch_bounds__(256) void k_L0(const float* __restrict__ x,
    const float* __restrict__ Wl0, const float* __restrict__ bl0,
    const float* __restrict__ Wr0, const float* __restrict__ br0,
    const float* __restrict__ att0, const float* __restrict__ bias0,
    const float* __restrict__ g0, const float* __restrict__ be0,
    const float* __restrict__ Wl1, const float* __restrict__ bl1,
    const float* __restrict__ Wr1, const float* __restrict__ br1,
    const int* __restrict__ list1, const int* __restrict__ rowptr0,
    const int* __restrict__ srcs0s, const int* __restrict__ flag2,
    const int* __restrict__ ctr,
    float* __restrict__ xl1, float* __restrict__ xr1buf){
  int tid = threadIdx.x;
  int h = tid >> 6, lane = tid & 63;
  __shared__ float s_wl0[256], s_att[256], s_base[256], s_hs[256], s_g[1024];
  __shared__ float s_red[4], s_A[4];
  // per-thread constants
  float wl0t = Wl0[tid], bl0t = bl0[tid], wr0t = Wr0[tid], br0t = br0[tid];
  float bs = bias0[tid], gv = g0[tid], bev = be0[tid];
  float bl1v = bl1[tid], br1v = br1[tid];
  s_wl0[tid] = wl0t;
  s_att[tid] = att0[tid];
  __syncthreads();
  int cnt1 = ctr[CTR_CNT1];
  for (int i = blockIdx.x; i < cnt1; i += gridDim.x){
    int v = list1[i];
    float xv0 = x[v];
    s_base[tid] = bl0t + fmaf(xv0, wr0t, br0t);   // bl0 + xr0[v]
    __syncthreads();
    int r0 = rowptr0[i], r1 = rowptr0[i + 1];     // slot r1 = synthetic self-loop
    // ---- edges-in-lanes logits, per-wave head, online softmax scalars ----
    float m = -INFINITY, Ssum = 0.f, Sx = 0.f;
    for (int c0 = r0; c0 <= r1; c0 += 64){
      int e = c0 + lane;
      bool valid = (e <= r1);
      int s = (e < r1) ? srcs0s[e] : v;
      float xs = x[s];
      float lg = -INFINITY;
      if (valid){
        lg = 0.f;
        #pragma unroll 8
        for (int c = 0; c < 64; ++c){
          int cc = h * 64 + c;
          float aa = fmaf(xs, s_wl0[cc], s_base[cc]);
          aa = (aa > 0.f) ? aa : 0.2f * aa;
          lg = fmaf(s_att[cc], aa, lg);
        }
      }
      float mc = wave_max(lg);
      float mn = fmaxf(m, mc);
      float sc = expf(m - mn);
      float p = valid ? expf(lg - mn) : 0.f;
      float Sc  = wave_sum(p);
      float Sxc = wave_sum(p * xs);
      Ssum = fmaf(Ssum, sc, Sc);
      Sx   = fmaf(Sx,   sc, Sxc);
      m = mn;
    }
    if (lane == 0) s_A[h] = Sx / (Ssum + 1e-16f);
    __syncthreads();
    // ---- closed-form output + bias + LN + ELU ----
    float o = fmaf(s_wl0[tid], s_A[h], bl0t) + bs;
    float s1 = wave_sum(o);
    if (lane == 0) s_red[h] = s1;
    __syncthreads();
    float mu = (s_red[0] + s_red[1] + s_red[2] + s_red[3]) * (1.f / 256.f);
    float dv = o - mu;
    __syncthreads();
    float s2 = wave_sum(dv * dv);
    if (lane == 0) s_red[h] = s2;
    __syncthreads();
    float var = (s_red[0] + s_red[1] + s_red[2] + s_red[3]) * (1.f / 256.f);
    float y = dv * rsqrtf(var + 1e-5f) * gv + bev;
    s_hs[tid] = (y > 0.f) ? y : expm1f(y);
    __syncthreads();
    // ---- fused layer-1 xl GEMV: k-split (wave=k-chunk), float4 outputs ----
    {
      int kc = h, q = lane;   // k-chunk = wave, 4 output channels per lane
      const float* Wb = Wl1 + (size_t)kc * 64 * 256 + 4 * q;
      float4 pa = {0.f, 0.f, 0.f, 0.f};
      #pragma unroll 8
      for (int k = 0; k < 64; ++k){
        float hk = s_hs[kc * 64 + k];
        float4 w = *reinterpret_cast<const float4*>(Wb + (size_t)k * 256);
        pa.x = fmaf(hk, w.x, pa.x); pa.y = fmaf(hk, w.y, pa.y);
        pa.z = fmaf(hk, w.z, pa.z); pa.w = fmaf(hk, w.w, pa.w);
      }
      reinterpret_cast<float4*>(s_g)[tid] = pa;  // s_g[kc*256 + ch]
      __syncthreads();
      float sum = s_g[tid] + s_g[256 + tid] + s_g[512 + tid] + s_g[768 + tid];
      xl1[(size_t)i * 256 + tid] = bl1v + sum;
    }
    int f2 = flag2[v];
    if (f2 > 0){
      __syncthreads();
      int kc = h, q = lane;
      const float* Wb = Wr1 + (size_t)kc * 64 * 256 + 4 * q;
      float4 pa = {0.f, 0.f, 0.f, 0.f};
      #pragma unroll 8
      for (int k = 0; k < 64; ++k){
        float hk = s_hs[kc * 64 + k];
        float4 w = *reinterpret_cast<const float4*>(Wb + (size_t)k * 256);
        pa.x = fmaf(hk, w.x, pa.x); pa.y = fmaf(hk, w.y, pa.y);
        pa.z = fmaf(hk, w.z, pa.z); pa.w = fmaf(hk, w.w, pa.w);
      }
      reinterpret_cast<float4*>(s_g)[tid] = pa;
      __syncthreads();
      float sum = s_g[tid] + s_g[256 + tid] + s_g[512 + tid] + s_g[768 + tid];
      xr1buf[(size_t)(f2 - 1) * 256 + tid] = br1v + sum;
    }
    __syncthreads();   // protect s_base/s_hs/s_g before next node
  }
}

// ---------------- L1: LDS-staged edges, lane-parallel logits, k-split GEMVs ----------------
#define L1CHUNK 48
__global__ __launch_bounds__(256) void k_L1(const float* __restrict__ xl1,
    const float* __restrict__ xr1buf,
    const float* __restrict__ att1, const float* __restrict__ bias1,
    const float* __restrict__ g1, const float* __restrict__ be1,
    const float* __restrict__ Wl2, const float* __restrict__ bl2,
    const float* __restrict__ Wr2, const float* __restrict__ br2,
    const int* __restrict__ rowptr1, const int* __restrict__ srcs1s,
    const int* __restrict__ ctr,
    float* __restrict__ xl2, float* __restrict__ xr2){
  int tid = threadIdx.x;
  int h = tid >> 6, lane = tid & 63;
  __shared__ float s_xl[L1CHUNK * 257];   // padded rows: bank-conflict-free column reads
  __shared__ float s_xr[256], s_att[256], s_hs[256], s_g[256];
  __shared__ int   s_si[L1CHUNK];
  __shared__ float s_red[4];
  s_att[tid] = att1[tid];
  float bs = bias1[tid], gv = g1[tid], bev = be1[tid];
  __syncthreads();
  int cnt2 = ctr[CTR_CNT2];
  for (int i = blockIdx.x; i < cnt2; i += gridDim.x){
    s_xr[tid] = xr1buf[(size_t)i * 256 + tid];
    int r0 = rowptr1[i], r1 = rowptr1[i + 1];   // slot r1 = synthetic self (a1idx == i)
    float m = -INFINITY, Ssum = 0.f, out_acc = 0.f;
    for (int c0 = r0; c0 <= r1; c0 += L1CHUNK){
      int n = min(L1CHUNK, r1 + 1 - c0);
      if (tid < n){
        int e = c0 + tid;
        s_si[tid] = (e < r1) ? srcs1s[e] : i;
      }
      __syncthreads();
      for (int jj = 0; jj < n; ++jj)
        s_xl[jj * 257 + tid] = xl1[(size_t)s_si[jj] * 256 + tid];
      __syncthreads();
      // lane j = edge j of chunk, wave h = head
      float lg = -INFINITY;
      if (lane < n){
        lg = 0.f;
        #pragma unroll 8
        for (int c = 0; c < 64; ++c){
          int cc = h * 64 + c;
          float aa = s_xl[lane * 257 + cc] + s_xr[cc];
          aa = (aa > 0.f) ? aa : 0.2f * aa;
          lg = fmaf(s_att[cc], aa, lg);
        }
      }
      float mc = wave_max(lg);
      float mn = fmaxf(m, mc);
      float sc = expf(m - mn);
      float p = (lane < n) ? expf(lg - mn) : 0.f;
      float Sc = wave_sum(p);
      Ssum = fmaf(Ssum, sc, Sc);
      float an = out_acc * sc;
      for (int j = 0; j < n; ++j){
        float pj = __shfl(p, j, 64);
        an = fmaf(pj, s_xl[j * 257 + tid], an);
      }
      out_acc = an;
      m = mn;
      __syncthreads();   // protect s_xl/s_si before next chunk
    }
    float o = out_acc / (Ssum + 1e-16f) + bs;
    float s1 = wave_sum(o);
    if (lane == 0) s_red[h] = s1;
    __syncthreads();
    float mu = (s_red[0] + s_red[1] + s_red[2] + s_red[3]) * (1.f / 256.f);
    float dv = o - mu;
    __syncthreads();
    float s2 = wave_sum(dv * dv);
    if (lane == 0) s_red[h] = s2;
    __syncthreads();
    float var = (s_red[0] + s_red[1] + s_red[2] + s_red[3]) * (1.f / 256.f);
    float y = dv * rsqrtf(var + 1e-5f) * gv + bev;
    s_hs[tid] = (y > 0.f) ? y : expm1f(y);
    __syncthreads();
    // fused layer-2 xl GEMV: k-split (wave = k-chunk of 64), 64 outputs
    {
      int kc = h, ch = lane;
      float acc = 0.f;
      #pragma unroll 8
      for (int k = 0; k < 64; ++k)
        acc = fmaf(s_hs[kc * 64 + k], Wl2[(size_t)(kc * 64 + k) * 64 + ch], acc);
      s_g[tid] = acc;
      __syncthreads();
      if (tid < 64)
        xl2[(size_t)i * 64 + tid] = bl2[tid] + s_g[tid] + s_g[64 + tid] + s_g[128 + tid] + s_g[192 + tid];
    }
    if (i == 0){
      __syncthreads();
      int kc = h, ch = lane;
      float acc = 0.f;
      #pragma unroll 8
      for (int k = 0; k < 64; ++k)
        acc = fmaf(s_hs[kc * 64 + k], Wr2[(size_t)(kc * 64 + k) * 64 + ch], acc);
      s_g[tid] = acc;
      __syncthreads();
      if (tid < 64)
        xr2[tid] = br2[tid] + s_g[tid] + s_g[64 + tid] + s_g[128 + tid] + s_g[192 + tid];
    }
    __syncthreads();
  }
}

// ---------------- final: layer-2 flash agg for node 0 + LN + ELU + head MLP ----------------
__global__ __launch_bounds__(64) void k_final(const float* __restrict__ xl2,
    const float* __restrict__ xr2,
    const float* __restrict__ att2, const float* __restrict__ bias2,
    const float* __restrict__ g2, const float* __restrict__ be2,
    const float* __restrict__ rw1, const float* __restrict__ rb1,
    const float* __restrict__ rw2, const float* __restrict__ rb2,
    const int* __restrict__ E2src, const int* __restrict__ flag2,
    const int* __restrict__ ctr, float* __restrict__ out){
  int lane = threadIdx.x;
  float xr = xr2[lane], at = att2[lane];
  int ne = ctr[CTR_E2];
  float m = -INFINITY, ssum = 0.f, acc = 0.f;
  for (int e = 0; e <= ne; ++e){
    int idx = (e < ne) ? (flag2[E2src[e]] - 1) : 0;
    float xls = xl2[(size_t)idx * 64 + lane];
    float a = xls + xr;
    a = (a > 0.f) ? a : 0.2f * a;
    float lg = wave_sum(at * a);
    float mn = fmaxf(m, lg);
    float sc = expf(m - mn), p = expf(lg - mn);
    ssum = fmaf(ssum, sc, p);
    acc  = fmaf(acc,  sc, p * xls);
    m = mn;
  }
  float o = acc / (ssum + 1e-16f) + bias2[lane];
  float mu = wave_sum(o) * (1.f / 64.f);
  float dv = o - mu;
  float var = wave_sum(dv * dv) * (1.f / 64.f);
  float y = dv * rsqrtf(var + 1e-5f) * g2[lane] + be2[lane];
  float hv_v = (y > 0.f) ? y : expm1f(y);
  __shared__ float hv[64];
  hv[lane] = hv_v;
  __syncthreads();
  float contrib = 0.f;
  if (lane < 32){
    float a = rb1[lane];
    #pragma unroll 8
    for (int c = 0; c < 64; ++c) a = fmaf(hv[c], rw1[c * 32 + lane], a);
    float z = 0.5f * a * (1.f + erff(a * 0.70710678118654752f));
    contrib = z * rw2[lane];
  }
  float sfin = wave_sum(contrib);
  if (lane == 0) out[0] = sfin + rb2[0];
}

// ---------------- launch ----------------
extern "C" void kernel_launch(void* const* d_in, const int* in_sizes, int n_in,
                              void* d_out, int out_size, void* d_ws, size_t ws_size,
                              hipStream_t stream){
  const float* x    = (const float*)d_in[0];
  const int*   ei   = (const int*)  d_in[1];
  const float* Wl0  = (const float*)d_in[2];
  const float* bl0  = (const float*)d_in[3];
  const float* Wr0  = (const float*)d_in[4];
  const float* br0  = (const float*)d_in[5];
  const float* att0 = (const float*)d_in[6];
  const float* bias0= (const float*)d_in[7];
  const float* Wl1  = (const float*)d_in[8];
  const float* bl1  = (const float*)d_in[9];
  const float* Wr1  = (const float*)d_in[10];
  const float* br1  = (const float*)d_in[11];
  const float* att1 = (const float*)d_in[12];
  const float* bias1= (const float*)d_in[13];
  const float* Wl2  = (const float*)d_in[14];
  const float* bl2  = (const float*)d_in[15];
  const float* Wr2  = (const float*)d_in[16];
  const float* br2  = (const float*)d_in[17];
  const float* att2 = (const float*)d_in[18];
  const float* bias2= (const float*)d_in[19];
  const float* g0   = (const float*)d_in[20];
  const float* be0  = (const float*)d_in[21];
  const float* g1   = (const float*)d_in[22];
  const float* be1  = (const float*)d_in[23];
  const float* g2   = (const float*)d_in[24];
  const float* be2  = (const float*)d_in[25];
  const float* rw1  = (const float*)d_in[26];
  const float* rb1  = (const float*)d_in[27];
  const float* rw2  = (const float*)d_in[28];
  const float* rb2  = (const float*)d_in[29];

  const int N = in_sizes[0];        // 50000
  const int E = in_sizes[1] / 2;    // 800000

  char* ws = (char*)d_ws;
  size_t off = 0;
  auto alloc = [&](size_t bytes) -> char* {
    char* p = ws + off;
    off += (bytes + 255) & ~(size_t)255;
    return p;
  };
  int*   ctr     = (int*)  alloc(64);
  int*   flag1   = (int*)  alloc((size_t)N * 4);
  int*   flag2   = (int*)  alloc((size_t)N * 4);
  int*   list1   = (int*)  alloc((size_t)N * 4);
  int*   list2   = (int*)  alloc((size_t)N * 4);
  int*   E2src   = (int*)  alloc((size_t)E * 4);
  int*   EBsrc   = (int*)  alloc((size_t)E * 4);
  int*   EBdst   = (int*)  alloc((size_t)E * 4);
  int*   ECsrc   = (int*)  alloc((size_t)E * 4);
  int*   ECdst   = (int*)  alloc((size_t)E * 4);
  int*   rowptr0 = (int*)  alloc((size_t)(N + 1) * 4);
  int*   rowptr1 = (int*)  alloc((size_t)(N + 1) * 4);
  int*   srcs0s  = (int*)  alloc((size_t)E * 4);
  int*   srcs1s  = (int*)  alloc((size_t)E * 4);
  float* xr2     = (float*)alloc(64 * 4);
  float* xl2     = (float*)alloc((size_t)N * 64 * 4);
  float* xl1     = (float*)alloc((size_t)N * 256 * 4);
  float* xr1buf  = (float*)alloc((size_t)N * 256 * 4);
  (void)ws_size; (void)n_in; (void)out_size;

  int nb = (N + 255) / 256;

  k_init      <<<nb, 256, 0, stream>>>(flag1, flag2, list2, ctr, N);
  k_passA     <<<256, 256, 0, stream>>>(ei, E, flag2, list2, E2src, ctr);
  k_seed      <<<1, 256, 0, stream>>>(list2, list1, flag1, ctr);
  k_passB     <<<256, 256, 0, stream>>>(ei, E, flag2, flag1, list1, EBsrc, EBdst, ctr);
  k_passC_regB<<<257, 256, 0, stream>>>(ei, E, flag1, ECsrc, ECdst, ctr,
                                        EBsrc, EBdst, rowptr1, srcs1s);
  k_regC      <<<1, 256, 0, stream>>>(ECsrc, ECdst, rowptr0, srcs0s, ctr);
  k_L0        <<<512, 256, 0, stream>>>(x, Wl0, bl0, Wr0, br0, att0, bias0, g0, be0,
                                        Wl1, bl1, Wr1, br1,
                                        list1, rowptr0, srcs0s, flag2, ctr, xl1, xr1buf);
  k_L1        <<<64, 256, 0, stream>>>(xl1, xr1buf, att1, bias1, g1, be1,
                                       Wl2, bl2, Wr2, br2,
                                       rowptr1, srcs1s, ctr, xl2, xr2);
  k_final     <<<1, 64, 0, stream>>>(xl2, xr2, att2, bias2, g2, be2,
                                     rw1, rb1, rw2, rb2, E2src, flag2, ctr, (float*)d_out);
}